// Round 8
// baseline (262.029 us; speedup 1.0000x reference)
//
#include <hip/hip_runtime.h>

typedef unsigned short u16;
typedef __attribute__((ext_vector_type(8))) short bf16x8;
typedef __attribute__((ext_vector_type(4))) float f32x4;

#define MFMA(a, b, c) __builtin_amdgcn_mfma_f32_16x16x32_bf16(a, b, c, 0, 0, 0)
#define LOG2E 1.44269504088896340736f

__device__ __forceinline__ u16 f2bf(float f) {
    union { float f; unsigned u; } v; v.f = f;
    unsigned r = v.u + 0x7fffu + ((v.u >> 16) & 1u);   // RNE
    return (u16)(r >> 16);
}
__device__ __forceinline__ float bf2f(u16 h) {
    union { unsigned u; float f; } v; v.u = ((unsigned)h) << 16;
    return v.f;
}
// single-instruction packed f32->bf16 (RNE). No builtin on gfx950 (m240);
// hand-asm is 1 VALU op vs ~10 for the software fallback. Verified R2/R4.
__device__ __forceinline__ unsigned pkbf(float a, float b) {
    unsigned r;
    asm("v_cvt_pk_bf16_f32 %0, %1, %2" : "=v"(r) : "v"(a), "v"(b));
    return r;
}
// single f32->bf16 via cvt_pk (same RNE bits as f2bf, 1 instr vs ~5)
__device__ __forceinline__ u16 cvt1bf(float a) {
    return (u16)pkbf(a, a);
}
__device__ __forceinline__ float ex2(float x) {
#if __has_builtin(__builtin_amdgcn_exp2f)
    return __builtin_amdgcn_exp2f(x);
#else
    return exp2f(x);
#endif
}
__device__ __forceinline__ bf16x8 frag_from(unsigned a, unsigned b, unsigned c, unsigned d) {
    uint4 v; v.x = a; v.y = b; v.z = c; v.w = d;
    return __builtin_bit_cast(bf16x8, v);
}

// async global->LDS, 16B per lane. LDS dest = wave-uniform base + lane*16.
__device__ __forceinline__ void g2l16(const void* g, void* lds_base) {
    __builtin_amdgcn_global_load_lds(
        (const __attribute__((address_space(1))) unsigned*)(unsigned long long)(uintptr_t)g,
        (__attribute__((address_space(3))) unsigned*)(unsigned)(uintptr_t)lds_base,
        16, 0, 0);
}

// ---- fused prep: x fp32->bf16 convert  +  3 weight transpose+converts ----
__global__ __launch_bounds__(256) void prep_kernel(
    const float* __restrict__ x, const float* __restrict__ wq,
    const float* __restrict__ wkv, const float* __restrict__ wp,
    u16* __restrict__ xb, u16* __restrict__ wtqkv, u16* __restrict__ wtp)
{
    int bz = blockIdx.x;
    int t = threadIdx.x;
    if (bz < 6144) {
        int i = (bz * 256 + t) * 4;
        float4 v = *(const float4*)&x[i];
        uint2 o;
        o.x = pkbf(v.x, v.y);
        o.y = pkbf(v.z, v.w);
        *(uint2*)&xb[i] = o;
        return;
    }
    __shared__ float tile[32][33];
    const float* W; u16* Wt; int cols; int r = bz - 6144;
    if (r < 576)       { W = wq;  Wt = wtqkv;             cols = 768;  }
    else if (r < 1728) { W = wkv; Wt = wtqkv + 768 * 768; cols = 1536; r -= 576; }
    else               { W = wp;  Wt = wtp;               cols = 768;  r -= 1728; }
    int nbx = cols / 32;
    int bx = (r % nbx) * 32, by = (r / nbx) * 32;
    int tx = t & 31, ty = t >> 5;
    for (int i = 0; i < 4; i++)
        tile[ty + 8 * i][tx] = W[(size_t)(by + ty + 8 * i) * cols + bx + tx];
    __syncthreads();
    for (int i = 0; i < 4; i++)
        Wt[(size_t)(bx + ty + 8 * i) * 768 + by + tx] = f2bf(tile[tx][ty + 8 * i]);
}

// ------- GEMM1: C[M][2304] = A[M][768]·Bt[2304][768]^T + bias, 128x128, BK=64.
// 1D grid 1152, XCD-compact swizzle.
// R8: smem 34816->32768 via 2-round epilogues => 5 blocks/CU (160KB exactly);
// all 1152 blocks co-resident -> serial 128-block tail eliminated. Q/K
// epilogue f2bf -> 1-instr cvt. (R7 counters: MfmaUtil 25 / VALU 16 / HBM 18%
// => latency/occupancy-bound, tail+drain dominated.)
__global__ __launch_bounds__(256, 5) void gemm128(
    const u16* __restrict__ A, const u16* __restrict__ Bt,
    const float* __restrict__ bias0, const float* __restrict__ bias1, int bsplit,
    u16* __restrict__ outB, u16* __restrict__ vtg, int M, int N, int K)
{
    __shared__ __align__(16) u16 smem[16384];   // 32,768 B
    u16* As = smem;
    u16* Bs = smem + 8192;
    u16* Cs = smem;

    int gid = blockIdx.x;
    int bmi = ((gid & 7) << 3) | ((gid >> 3) & 7);   // 0..63
    int bni = gid >> 6;                               // 0..17
    int bm = bmi * 128, bn = bni * 128;

    int t = threadIdx.x;
    int w = t >> 6, l = t & 63, q4 = l >> 4, lm = l & 15, lm7 = l & 7;
    int wm = (w >> 1) * 64, wn = (w & 1) * 64;

    f32x4 acc[4][4];
    for (int i = 0; i < 4; i++) for (int j = 0; j < 4; j++) acc[i][j] = (f32x4){0, 0, 0, 0};

    int srow = l >> 3;
    int schunk = (l & 7) ^ srow;

    for (int kt = 0; kt < K; kt += 64) {
        for (int p = 0; p < 4; p++) {
            int row = p * 32 + w * 8 + srow;
            g2l16(&A [(size_t)(bm + row) * K + kt + schunk * 8], &As[(p * 32 + w * 8) * 64]);
            g2l16(&Bt[(size_t)(bn + row) * K + kt + schunk * 8], &Bs[(p * 32 + w * 8) * 64]);
        }
        __syncthreads();
        for (int kc = 0; kc < 2; kc++) {
            bf16x8 a[4], b[4];
            for (int i = 0; i < 4; i++)
                a[i] = *(const bf16x8*)&As[(wm + 16 * i + lm) * 64 + ((4 * kc + q4) ^ lm7) * 8];
            for (int j = 0; j < 4; j++)
                b[j] = *(const bf16x8*)&Bs[(wn + 16 * j + lm) * 64 + ((4 * kc + q4) ^ lm7) * 8];
            for (int i = 0; i < 4; i++)
                for (int j = 0; j < 4; j++)
                    acc[i][j] = MFMA(a[i], b[j], acc[i][j]);
        }
        __syncthreads();
    }

    if (bn < 1536) {
        // Q/K: row-major repack, TWO 64-row rounds (Cs = 64x132 u16 = 16.9 KB)
        for (int round = 0; round < 2; round++) {
            if (round) __syncthreads();
            if ((w >> 1) == round) {
                for (int i = 0; i < 4; i++)
                    for (int j = 0; j < 4; j++) {
                        int col = bn + wn + 16 * j + lm;
                        float bv = (col < bsplit) ? bias0[col] : bias1[col - bsplit];
                        for (int r = 0; r < 4; r++) {
                            float v = acc[i][j][r] + bv;
                            Cs[(16 * i + 4 * q4 + r) * 132 + wn + 16 * j + lm] = cvt1bf(v);
                        }
                    }
            }
            __syncthreads();
            int row = t >> 2, sub = t & 3;
            for (int s = 0; s < 4; s++)
                *(uint4*)&outB[(size_t)(bm + round * 64 + row) * N + bn + sub * 8 + s * 32] =
                    *(const uint4*)&Cs[row * 132 + sub * 8 + s * 32];
        }
    } else {
        // V: TRANSPOSED repack, TWO 64-n rounds (Cs2 = 128x68 u16 = 17.4 KB)
        int cfull = t >> 1, o2 = t & 1;
        int d = cfull & 63, hloc = cfull >> 6;
        int b = bm >> 11;
        int bh = b * 12 + ((bn - 1536) >> 6) + hloc;
        for (int round = 0; round < 2; round++) {
            if (round) __syncthreads();
            if ((w >> 1) == round) {
                for (int i = 0; i < 4; i++)
                    for (int j = 0; j < 4; j++) {
                        int cl = wn + 16 * j + lm;
                        float bv = bias1[bn + cl - bsplit];
                        uint2 pk;
                        pk.x = pkbf(acc[i][j][0] + bv, acc[i][j][1] + bv);
                        pk.y = pkbf(acc[i][j][2] + bv, acc[i][j][3] + bv);
                        *(uint2*)&Cs[cl * 68 + 16 * i + 4 * q4] = pk;
                    }
            }
            __syncthreads();
            size_t rowoff = ((size_t)bh * 64 + d) * 2048 + (bm & 2047) + round * 64;
            const u16* base = &Cs[cfull * 68];
            for (int o = 0; o < 4; o++) {
                int oct = o2 * 4 + o;
                int n0 = 32 * (oct >> 2) + 4 * (oct & 3);
                uint2 lo = *(const uint2*)&base[n0];
                uint2 hi = *(const uint2*)&base[n0 + 16];
                uint4 ov; ov.x = lo.x; ov.y = lo.y; ov.z = hi.x; ov.w = hi.y;
                *(uint4*)&vtg[rowoff + oct * 8] = ov;
            }
        }
    }
}

// ------- GEMM2: out[M][768] fp32 = A[M][K]·Bt[768][K]^T + bias. 128x64 tile, BK=64.
// 1D grid 768, XCD-compact swizzle. Epilogue: 2 half-tile LDS rounds.
__global__ __launch_bounds__(256, 4) void gemm_n64(
    const u16* __restrict__ A, const u16* __restrict__ Bt,
    const float* __restrict__ bias, float* __restrict__ outF, int M, int N, int K)
{
    __shared__ __align__(16) u16 smem[12288];   // 24 KB: As[128][64] | Bs[64][64]
    u16* As = smem;
    u16* Bs = smem + 8192;
    float* Cf = (float*)smem;                   // [64][68] fp32 per epilogue round (17.4 KB)

    int gid = blockIdx.x;
    int bmi = ((gid & 7) << 3) | ((gid >> 3) & 7);   // 0..63
    int bni = gid >> 6;                               // 0..11
    int bm = bmi * 128, bn = bni * 64;

    int t = threadIdx.x;
    int w = t >> 6, l = t & 63, q4 = l >> 4, lm = l & 15, lm7 = l & 7;
    int wm = (w >> 1) * 64, wn = (w & 1) * 32;

    f32x4 acc[4][2];
    for (int i = 0; i < 4; i++) for (int j = 0; j < 2; j++) acc[i][j] = (f32x4){0, 0, 0, 0};

    int srow = l >> 3;
    int schunk = (l & 7) ^ srow;

    for (int kt = 0; kt < K; kt += 64) {
        for (int p = 0; p < 4; p++) {
            int row = p * 32 + w * 8 + srow;
            g2l16(&A[(size_t)(bm + row) * K + kt + schunk * 8], &As[(p * 32 + w * 8) * 64]);
        }
        for (int p = 0; p < 2; p++) {
            int row = p * 32 + w * 8 + srow;
            g2l16(&Bt[(size_t)(bn + row) * K + kt + schunk * 8], &Bs[(p * 32 + w * 8) * 64]);
        }
        __syncthreads();
        for (int kc = 0; kc < 2; kc++) {
            bf16x8 a[4], b[2];
            for (int i = 0; i < 4; i++)
                a[i] = *(const bf16x8*)&As[(wm + 16 * i + lm) * 64 + ((4 * kc + q4) ^ lm7) * 8];
            for (int j = 0; j < 2; j++)
                b[j] = *(const bf16x8*)&Bs[(wn + 16 * j + lm) * 64 + ((4 * kc + q4) ^ lm7) * 8];
            for (int i = 0; i < 4; i++)
                for (int j = 0; j < 2; j++)
                    acc[i][j] = MFMA(a[i], b[j], acc[i][j]);
        }
        __syncthreads();
    }

    // epilogue: two 64-row half-tiles via LDS, fully-coalesced float4 stores
    for (int round = 0; round < 2; round++) {
        if (round) __syncthreads();
        if ((w >> 1) == round) {
            for (int i = 0; i < 4; i++)
                for (int j = 0; j < 2; j++) {
                    int cl = wn + 16 * j + lm;
                    float bv = bias[bn + cl];
                    for (int r = 0; r < 4; r++)
                        Cf[(16 * i + 4 * q4 + r) * 68 + cl] = acc[i][j][r] + bv;
                }
        }
        __syncthreads();
        int row = t >> 4, c4 = (t & 15) * 4;
        for (int s = 0; s < 4; s++) {
            int rr = row + s * 16;
            *(float4*)&outF[(size_t)(bm + round * 64 + rr) * N + bn + c4] =
                *(const float4*)&Cf[rr * 68 + c4];
        }
    }
}

// ---------------- fused flash attention ----------------
// R8 = R6 attn (single 768-block launch; split reverted: +13 µs cost, info
// gained). Structure is issue-saturated (MfmaUtil 44 + VALUBusy 44 + DS 12 =
// 100% — per-SIMD issue port is the binding resource; stagger/setprio nulls
// confirm). Ceiling within this structure = total issued cycles.
__global__ __launch_bounds__(256, 3) void attn_kernel(const u16* __restrict__ qkv,
                                                      const u16* __restrict__ vtg,
                                                      u16* __restrict__ xatt)
{
    __shared__ __align__(16) u16 smem[16384];   // 32,768 B

    int gid = blockIdx.x;
    int bh = gid % 48, qt = gid / 48;
    int b = bh / 12, h = bh % 12;

    int t = threadIdx.x;
    int w = t >> 6, l = t & 63, q4 = l >> 4, lm = l & 15, lm7 = l & 7;
    int qw = qt * 128 + w * 32;
    size_t rowbase = (size_t)b * 2048;

    int srow = l >> 3;
    int schunk = (l & 7) ^ srow;
    const u16* kp[2];
    const u16* vp[2];
    for (int p = 0; p < 2; p++) {
        int row = w * 16 + p * 8 + srow;
        kp[p] = &qkv[(rowbase + row) * 2304 + 768 + h * 64 + schunk * 8];
        vp[p] = &vtg[((size_t)bh * 64 + row) * 2048 + schunk * 8];
    }

    bf16x8 qf[2][2];
    for (int qi = 0; qi < 2; qi++) {
        size_t row = rowbase + qw + 16 * qi + lm;
        for (int kq = 0; kq < 2; kq++) {
            bf16x8 raw = *(const bf16x8*)&qkv[row * 2304 + h * 64 + kq * 32 + q4 * 8];
            bf16x8 sc;
            for (int j = 0; j < 8; j++) sc[j] = (short)f2bf(bf2f((u16)raw[j]) * (0.125f * LOG2E));
            qf[qi][kq] = sc;
        }
    }

    // all-ones bf16 B-fragment for the denominator MFMA
    const bf16x8 ONES = frag_from(0x3F803F80u, 0x3F803F80u, 0x3F803F80u, 0x3F803F80u);

    int offA = lm * 64 + (q4 ^ lm7) * 8;
    int offB = lm * 64 + ((4 | q4) ^ lm7) * 8;

    f32x4 acc[2][4];
    f32x4 acc_l[2];
    for (int qi = 0; qi < 2; qi++) {
        for (int dt = 0; dt < 4; dt++) acc[qi][dt] = (f32x4){0, 0, 0, 0};
        acc_l[qi] = (f32x4){0, 0, 0, 0};
    }

    for (int p = 0; p < 2; p++) {
        g2l16(kp[p], smem + (w * 16 + p * 8) * 64);
        g2l16(vp[p], smem + 8192 + (w * 16 + p * 8) * 64);
    }

    const size_t KSTEP = (size_t)64 * 2304;
    for (int it = 0; it < 32; it++) {
        __syncthreads();
        int buf = it & 1;
        if (it + 1 < 32) {
            int nbuf = buf ^ 1;
            for (int p = 0; p < 2; p++) {
                kp[p] += KSTEP;
                vp[p] += 64;
                g2l16(kp[p], smem + nbuf * 4096 + (w * 16 + p * 8) * 64);
                g2l16(vp[p], smem + 8192 + nbuf * 4096 + (w * 16 + p * 8) * 64);
            }
        }
        const u16* Kb = smem + buf * 4096;
        const u16* Vb = smem + 8192 + buf * 4096;

        f32x4 s[2][4];
        for (int kt2 = 0; kt2 < 4; kt2++) {
            bf16x8 kf0 = *(const bf16x8*)&Kb[kt2 * 1024 + offA];
            bf16x8 kf1 = *(const bf16x8*)&Kb[kt2 * 1024 + offB];
            for (int qi = 0; qi < 2; qi++) {
                f32x4 z = {0, 0, 0, 0};
                z = MFMA(kf0, qf[qi][0], z);
                z = MFMA(kf1, qf[qi][1], z);
                s[qi][kt2] = z;
            }
        }

        bf16x8 vf0[4], vf1[4];
        for (int dt = 0; dt < 4; dt++) {
            vf0[dt] = *(const bf16x8*)&Vb[dt * 1024 + offA];
            vf1[dt] = *(const bf16x8*)&Vb[dt * 1024 + offB];
        }

        for (int qi = 0; qi < 2; qi++) {
            uint2 pk[4];
            for (int kt2 = 0; kt2 < 4; kt2++) {
                float p0 = ex2(s[qi][kt2][0]);
                float p1 = ex2(s[qi][kt2][1]);
                float p2 = ex2(s[qi][kt2][2]);
                float p3 = ex2(s[qi][kt2][3]);
                pk[kt2].x = pkbf(p0, p1);
                pk[kt2].y = pkbf(p2, p3);
            }

            bf16x8 af0 = frag_from(pk[0].x, pk[0].y, pk[1].x, pk[1].y);
            bf16x8 af1 = frag_from(pk[2].x, pk[2].y, pk[3].x, pk[3].y);
            for (int dt = 0; dt < 4; dt++) {
                acc[qi][dt] = MFMA(af0, vf0[dt], acc[qi][dt]);
                acc[qi][dt] = MFMA(af1, vf1[dt], acc[qi][dt]);
            }
            // denominator on the MFMA pipe (ones-column trick)
            acc_l[qi] = MFMA(af0, ONES, acc_l[qi]);
            acc_l[qi] = MFMA(af1, ONES, acc_l[qi]);
        }
    }

    for (int qi = 0; qi < 2; qi++) {
        float ar[4];
        for (int r = 0; r < 4; r++) ar[r] = 1.0f / acc_l[qi][r];
        for (int dt = 0; dt < 4; dt++)
            for (int r = 0; r < 4; r++) {
                int row = qw + 16 * qi + 4 * q4 + r;
                xatt[(rowbase + row) * 768 + h * 64 + 16 * dt + lm] =
                    f2bf(acc[qi][dt][r] * ar[r]);
            }
    }
}

extern "C" void kernel_launch(void* const* d_in, const int* in_sizes, int n_in,
                              void* d_out, int out_size, void* d_ws, size_t ws_size,
                              hipStream_t stream)
{
    const float* x   = (const float*)d_in[0];
    const float* wq  = (const float*)d_in[1];
    const float* bq  = (const float*)d_in[2];
    const float* wkv = (const float*)d_in[3];
    const float* bkv = (const float*)d_in[4];
    const float* wp  = (const float*)d_in[5];
    const float* bp  = (const float*)d_in[6];
    float* out = (float*)d_out;

    char* ws = (char*)d_ws;
    u16* xb    = (u16*)(ws);                  // x bf16        [8192][768]   12.6 MB
    u16* wtqkv = (u16*)(ws + 12582912);       // W_qkv^T bf16  [2304][768]    3.5 MB
    u16* wtp   = (u16*)(ws + 16121856);       // W_p^T bf16    [768][768]     1.2 MB
    u16* qkvb  = (u16*)(ws + 17301504);       // q|k bf16      [8192][2304]  37.7 MB (V cols unused)
    u16* xatt  = (u16*)(ws + 55050240);       // attn out bf16 [8192][768]   12.6 MB
    u16* vtg   = (u16*)(ws + 67632128);       // V^T bf16 [48][64][2048]     12.6 MB

    prep_kernel<<<8448, 256, 0, stream>>>(x, wq, wkv, wp, xb, wtqkv, wtp);

    gemm128<<<1152, 256, 0, stream>>>(
        xb, wtqkv, bq, bkv, 768, qkvb, vtg, 8192, 2304, 768);

    attn_kernel<<<768, 256, 0, stream>>>(qkvb, vtg, xatt);

    gemm_n64<<<768, 256, 0, stream>>>(
        xatt, wtp, bp, out, 8192, 768, 768);
}

// Round 10
// 192.168 us; speedup vs baseline: 1.3635x; 1.3635x over previous
//
#include <hip/hip_runtime.h>

typedef unsigned short u16;
typedef __attribute__((ext_vector_type(8))) short bf16x8;
typedef __attribute__((ext_vector_type(4))) float f32x4;

#define MFMA(a, b, c) __builtin_amdgcn_mfma_f32_16x16x32_bf16(a, b, c, 0, 0, 0)
#define LOG2E 1.44269504088896340736f

__device__ __forceinline__ u16 f2bf(float f) {
    union { float f; unsigned u; } v; v.f = f;
    unsigned r = v.u + 0x7fffu + ((v.u >> 16) & 1u);   // RNE
    return (u16)(r >> 16);
}
__device__ __forceinline__ float bf2f(u16 h) {
    union { unsigned u; float f; } v; v.u = ((unsigned)h) << 16;
    return v.f;
}
// single-instruction packed f32->bf16 (RNE). No builtin on gfx950 (m240);
// hand-asm is 1 VALU op vs ~10 for the software fallback. Verified R2/R4.
__device__ __forceinline__ unsigned pkbf(float a, float b) {
    unsigned r;
    asm("v_cvt_pk_bf16_f32 %0, %1, %2" : "=v"(r) : "v"(a), "v"(b));
    return r;
}
// single f32->bf16 via cvt_pk (same RNE bits as f2bf, 1 instr vs ~5)
__device__ __forceinline__ u16 cvt1bf(float a) {
    return (u16)pkbf(a, a);
}
__device__ __forceinline__ float ex2(float x) {
#if __has_builtin(__builtin_amdgcn_exp2f)
    return __builtin_amdgcn_exp2f(x);
#else
    return exp2f(x);
#endif
}
__device__ __forceinline__ bf16x8 frag_from(unsigned a, unsigned b, unsigned c, unsigned d) {
    uint4 v; v.x = a; v.y = b; v.z = c; v.w = d;
    return __builtin_bit_cast(bf16x8, v);
}

// async global->LDS, 16B per lane. LDS dest = wave-uniform base + lane*16.
__device__ __forceinline__ void g2l16(const void* g, void* lds_base) {
    __builtin_amdgcn_global_load_lds(
        (const __attribute__((address_space(1))) unsigned*)(unsigned long long)(uintptr_t)g,
        (__attribute__((address_space(3))) unsigned*)(unsigned)(uintptr_t)lds_base,
        16, 0, 0);
}

// ---- fused prep: x fp32->bf16 convert  +  3 weight transpose+converts ----
__global__ __launch_bounds__(256) void prep_kernel(
    const float* __restrict__ x, const float* __restrict__ wq,
    const float* __restrict__ wkv, const float* __restrict__ wp,
    u16* __restrict__ xb, u16* __restrict__ wtqkv, u16* __restrict__ wtp)
{
    int bz = blockIdx.x;
    int t = threadIdx.x;
    if (bz < 6144) {
        int i = (bz * 256 + t) * 4;
        float4 v = *(const float4*)&x[i];
        uint2 o;
        o.x = pkbf(v.x, v.y);
        o.y = pkbf(v.z, v.w);
        *(uint2*)&xb[i] = o;
        return;
    }
    __shared__ float tile[32][33];
    const float* W; u16* Wt; int cols; int r = bz - 6144;
    if (r < 576)       { W = wq;  Wt = wtqkv;             cols = 768;  }
    else if (r < 1728) { W = wkv; Wt = wtqkv + 768 * 768; cols = 1536; r -= 576; }
    else               { W = wp;  Wt = wtp;               cols = 768;  r -= 1728; }
    int nbx = cols / 32;
    int bx = (r % nbx) * 32, by = (r / nbx) * 32;
    int tx = t & 31, ty = t >> 5;
    for (int i = 0; i < 4; i++)
        tile[ty + 8 * i][tx] = W[(size_t)(by + ty + 8 * i) * cols + bx + tx];
    __syncthreads();
    for (int i = 0; i < 4; i++)
        Wt[(size_t)(bx + ty + 8 * i) * 768 + by + tx] = cvt1bf(tile[tx][ty + 8 * i]);
}

// ------- GEMM1: C[M][2304] = A[M][768]·Bt[2304][768]^T + bias, 128x128, BK=64.
// 1D grid 1152, XCD-compact swizzle. R10 = resubmit of R9 (infra failure).
// Exact R7 structure (proven 43 µs): 34,816 B LDS, launch_bounds(256,4).
// R8 lesson: (256,5) caps VGPR at ~102 < 128 needed (64 arch + 64 AGPR acc,
// unified file) -> acc spilled to scratch (WRITE_SIZE 241 MB, MfmaUtil 0.6%).
// Only change vs R7: epilogue f2bf -> cvt1bf (1 instr, same RNE bits).
__global__ __launch_bounds__(256, 4) void gemm128(
    const u16* __restrict__ A, const u16* __restrict__ Bt,
    const float* __restrict__ bias0, const float* __restrict__ bias1, int bsplit,
    u16* __restrict__ outB, u16* __restrict__ vtg, int M, int N, int K)
{
    __shared__ __align__(16) u16 smem[17408];   // 34,816 B
    u16* As = smem;
    u16* Bs = smem + 8192;
    u16* Cs = smem;

    int gid = blockIdx.x;
    int bmi = ((gid & 7) << 3) | ((gid >> 3) & 7);   // 0..63
    int bni = gid >> 6;                               // 0..17
    int bm = bmi * 128, bn = bni * 128;

    int t = threadIdx.x;
    int w = t >> 6, l = t & 63, q4 = l >> 4, lm = l & 15, lm7 = l & 7;
    int wm = (w >> 1) * 64, wn = (w & 1) * 64;

    f32x4 acc[4][4];
    for (int i = 0; i < 4; i++) for (int j = 0; j < 4; j++) acc[i][j] = (f32x4){0, 0, 0, 0};

    int srow = l >> 3;
    int schunk = (l & 7) ^ srow;

    for (int kt = 0; kt < K; kt += 64) {
        for (int p = 0; p < 4; p++) {
            int row = p * 32 + w * 8 + srow;
            g2l16(&A [(size_t)(bm + row) * K + kt + schunk * 8], &As[(p * 32 + w * 8) * 64]);
            g2l16(&Bt[(size_t)(bn + row) * K + kt + schunk * 8], &Bs[(p * 32 + w * 8) * 64]);
        }
        __syncthreads();
        for (int kc = 0; kc < 2; kc++) {
            bf16x8 a[4], b[4];
            for (int i = 0; i < 4; i++)
                a[i] = *(const bf16x8*)&As[(wm + 16 * i + lm) * 64 + ((4 * kc + q4) ^ lm7) * 8];
            for (int j = 0; j < 4; j++)
                b[j] = *(const bf16x8*)&Bs[(wn + 16 * j + lm) * 64 + ((4 * kc + q4) ^ lm7) * 8];
            for (int i = 0; i < 4; i++)
                for (int j = 0; j < 4; j++)
                    acc[i][j] = MFMA(a[i], b[j], acc[i][j]);
        }
        __syncthreads();
    }

    if (bn < 1536) {
        // Q/K: row-major repack (stride 132) then coalesced b128 stores
        for (int i = 0; i < 4; i++)
            for (int j = 0; j < 4; j++) {
                int col = bn + wn + 16 * j + lm;
                float bv = (col < bsplit) ? bias0[col] : bias1[col - bsplit];
                for (int r = 0; r < 4; r++)
                    Cs[(wm + 16 * i + 4 * q4 + r) * 132 + wn + 16 * j + lm] =
                        cvt1bf(acc[i][j][r] + bv);
            }
        __syncthreads();
        int row = t >> 1, c0 = (t & 1) * 8;
        for (int s = 0; s < 8; s++)
            *(uint4*)&outB[(size_t)(bm + row) * N + bn + c0 + s * 16] =
                *(const uint4*)&Cs[row * 132 + c0 + s * 16];
    } else {
        // V: TRANSPOSED repack Cs[col][row] (packed b64 writes along rows)
        for (int i = 0; i < 4; i++)
            for (int j = 0; j < 4; j++) {
                int cl = wn + 16 * j + lm;
                float bv = bias1[bn + cl - bsplit];
                uint2 pk;
                pk.x = pkbf(acc[i][j][0] + bv, acc[i][j][1] + bv);
                pk.y = pkbf(acc[i][j][2] + bv, acc[i][j][3] + bv);
                *(uint2*)&Cs[cl * 132 + wm + 16 * i + 4 * q4] = pk;
            }
        __syncthreads();
        int c = t >> 1, half = t & 1;
        int d = c & 63, hloc = c >> 6;
        int b = bm >> 11;
        int bh = b * 12 + ((bn - 1536) >> 6) + hloc;
        size_t rowoff = ((size_t)bh * 64 + d) * 2048 + (bm & 2047) + half * 64;
        const u16* base = &Cs[c * 132 + half * 64];
        for (int oct = 0; oct < 8; oct++) {
            int n0 = 32 * (oct >> 2) + 4 * (oct & 3);
            uint2 lo = *(const uint2*)&base[n0];
            uint2 hi = *(const uint2*)&base[n0 + 16];
            uint4 o; o.x = lo.x; o.y = lo.y; o.z = hi.x; o.w = hi.y;
            *(uint4*)&vtg[rowoff + oct * 8] = o;
        }
    }
}

// ------- GEMM2: out[M][768] fp32 = A[M][K]·Bt[768][K]^T + bias. 128x64 tile, BK=64.
// 1D grid 768, XCD-compact swizzle. Epilogue: 2 half-tile LDS rounds.
__global__ __launch_bounds__(256, 4) void gemm_n64(
    const u16* __restrict__ A, const u16* __restrict__ Bt,
    const float* __restrict__ bias, float* __restrict__ outF, int M, int N, int K)
{
    __shared__ __align__(16) u16 smem[12288];   // 24 KB: As[128][64] | Bs[64][64]
    u16* As = smem;
    u16* Bs = smem + 8192;
    float* Cf = (float*)smem;                   // [64][68] fp32 per epilogue round (17.4 KB)

    int gid = blockIdx.x;
    int bmi = ((gid & 7) << 3) | ((gid >> 3) & 7);   // 0..63
    int bni = gid >> 6;                               // 0..11
    int bm = bmi * 128, bn = bni * 64;

    int t = threadIdx.x;
    int w = t >> 6, l = t & 63, q4 = l >> 4, lm = l & 15, lm7 = l & 7;
    int wm = (w >> 1) * 64, wn = (w & 1) * 32;

    f32x4 acc[4][2];
    for (int i = 0; i < 4; i++) for (int j = 0; j < 2; j++) acc[i][j] = (f32x4){0, 0, 0, 0};

    int srow = l >> 3;
    int schunk = (l & 7) ^ srow;

    for (int kt = 0; kt < K; kt += 64) {
        for (int p = 0; p < 4; p++) {
            int row = p * 32 + w * 8 + srow;
            g2l16(&A[(size_t)(bm + row) * K + kt + schunk * 8], &As[(p * 32 + w * 8) * 64]);
        }
        for (int p = 0; p < 2; p++) {
            int row = p * 32 + w * 8 + srow;
            g2l16(&Bt[(size_t)(bn + row) * K + kt + schunk * 8], &Bs[(p * 32 + w * 8) * 64]);
        }
        __syncthreads();
        for (int kc = 0; kc < 2; kc++) {
            bf16x8 a[4], b[2];
            for (int i = 0; i < 4; i++)
                a[i] = *(const bf16x8*)&As[(wm + 16 * i + lm) * 64 + ((4 * kc + q4) ^ lm7) * 8];
            for (int j = 0; j < 2; j++)
                b[j] = *(const bf16x8*)&Bs[(wn + 16 * j + lm) * 64 + ((4 * kc + q4) ^ lm7) * 8];
            for (int i = 0; i < 4; i++)
                for (int j = 0; j < 2; j++)
                    acc[i][j] = MFMA(a[i], b[j], acc[i][j]);
        }
        __syncthreads();
    }

    // epilogue: two 64-row half-tiles via LDS, fully-coalesced float4 stores
    for (int round = 0; round < 2; round++) {
        if (round) __syncthreads();
        if ((w >> 1) == round) {
            for (int i = 0; i < 4; i++)
                for (int j = 0; j < 2; j++) {
                    int cl = wn + 16 * j + lm;
                    float bv = bias[bn + cl];
                    for (int r = 0; r < 4; r++)
                        Cf[(16 * i + 4 * q4 + r) * 68 + cl] = acc[i][j][r] + bv;
                }
        }
        __syncthreads();
        int row = t >> 4, c4 = (t & 15) * 4;
        for (int s = 0; s < 4; s++) {
            int rr = row + s * 16;
            *(float4*)&outF[(size_t)(bm + round * 64 + rr) * N + bn + c4] =
                *(const float4*)&Cf[rr * 68 + c4];
        }
    }
}

// ---------------- fused flash attention ----------------
// R10 = exact R6 attn (proven 54.0 µs). Issue-saturated (MfmaUtil 44 +
// VALUBusy 44 + DS 12 = 100%); stagger/setprio nulls confirm the binding
// resource is per-SIMD issued work. Further gain requires a structural
// rewrite, deliberately not bundled with this recovery.
__global__ __launch_bounds__(256, 3) void attn_kernel(const u16* __restrict__ qkv,
                                                      const u16* __restrict__ vtg,
                                                      u16* __restrict__ xatt)
{
    __shared__ __align__(16) u16 smem[16384];   // 32,768 B

    int gid = blockIdx.x;
    int bh = gid % 48, qt = gid / 48;
    int b = bh / 12, h = bh % 12;

    int t = threadIdx.x;
    int w = t >> 6, l = t & 63, q4 = l >> 4, lm = l & 15, lm7 = l & 7;
    int qw = qt * 128 + w * 32;
    size_t rowbase = (size_t)b * 2048;

    int srow = l >> 3;
    int schunk = (l & 7) ^ srow;
    const u16* kp[2];
    const u16* vp[2];
    for (int p = 0; p < 2; p++) {
        int row = w * 16 + p * 8 + srow;
        kp[p] = &qkv[(rowbase + row) * 2304 + 768 + h * 64 + schunk * 8];
        vp[p] = &vtg[((size_t)bh * 64 + row) * 2048 + schunk * 8];
    }

    bf16x8 qf[2][2];
    for (int qi = 0; qi < 2; qi++) {
        size_t row = rowbase + qw + 16 * qi + lm;
        for (int kq = 0; kq < 2; kq++) {
            bf16x8 raw = *(const bf16x8*)&qkv[row * 2304 + h * 64 + kq * 32 + q4 * 8];
            bf16x8 sc;
            for (int j = 0; j < 8; j++) sc[j] = (short)f2bf(bf2f((u16)raw[j]) * (0.125f * LOG2E));
            qf[qi][kq] = sc;
        }
    }

    // all-ones bf16 B-fragment for the denominator MFMA
    const bf16x8 ONES = frag_from(0x3F803F80u, 0x3F803F80u, 0x3F803F80u, 0x3F803F80u);

    int offA = lm * 64 + (q4 ^ lm7) * 8;
    int offB = lm * 64 + ((4 | q4) ^ lm7) * 8;

    f32x4 acc[2][4];
    f32x4 acc_l[2];
    for (int qi = 0; qi < 2; qi++) {
        for (int dt = 0; dt < 4; dt++) acc[qi][dt] = (f32x4){0, 0, 0, 0};
        acc_l[qi] = (f32x4){0, 0, 0, 0};
    }

    for (int p = 0; p < 2; p++) {
        g2l16(kp[p], smem + (w * 16 + p * 8) * 64);
        g2l16(vp[p], smem + 8192 + (w * 16 + p * 8) * 64);
    }

    const size_t KSTEP = (size_t)64 * 2304;
    for (int it = 0; it < 32; it++) {
        __syncthreads();
        int buf = it & 1;
        if (it + 1 < 32) {
            int nbuf = buf ^ 1;
            for (int p = 0; p < 2; p++) {
                kp[p] += KSTEP;
                vp[p] += 64;
                g2l16(kp[p], smem + nbuf * 4096 + (w * 16 + p * 8) * 64);
                g2l16(vp[p], smem + 8192 + nbuf * 4096 + (w * 16 + p * 8) * 64);
            }
        }
        const u16* Kb = smem + buf * 4096;
        const u16* Vb = smem + 8192 + buf * 4096;

        f32x4 s[2][4];
        for (int kt2 = 0; kt2 < 4; kt2++) {
            bf16x8 kf0 = *(const bf16x8*)&Kb[kt2 * 1024 + offA];
            bf16x8 kf1 = *(const bf16x8*)&Kb[kt2 * 1024 + offB];
            for (int qi = 0; qi < 2; qi++) {
                f32x4 z = {0, 0, 0, 0};
                z = MFMA(kf0, qf[qi][0], z);
                z = MFMA(kf1, qf[qi][1], z);
                s[qi][kt2] = z;
            }
        }

        bf16x8 vf0[4], vf1[4];
        for (int dt = 0; dt < 4; dt++) {
            vf0[dt] = *(const bf16x8*)&Vb[dt * 1024 + offA];
            vf1[dt] = *(const bf16x8*)&Vb[dt * 1024 + offB];
        }

        for (int qi = 0; qi < 2; qi++) {
            uint2 pk[4];
            for (int kt2 = 0; kt2 < 4; kt2++) {
                float p0 = ex2(s[qi][kt2][0]);
                float p1 = ex2(s[qi][kt2][1]);
                float p2 = ex2(s[qi][kt2][2]);
                float p3 = ex2(s[qi][kt2][3]);
                pk[kt2].x = pkbf(p0, p1);
                pk[kt2].y = pkbf(p2, p3);
            }

            bf16x8 af0 = frag_from(pk[0].x, pk[0].y, pk[1].x, pk[1].y);
            bf16x8 af1 = frag_from(pk[2].x, pk[2].y, pk[3].x, pk[3].y);
            for (int dt = 0; dt < 4; dt++) {
                acc[qi][dt] = MFMA(af0, vf0[dt], acc[qi][dt]);
                acc[qi][dt] = MFMA(af1, vf1[dt], acc[qi][dt]);
            }
            // denominator on the MFMA pipe (ones-column trick)
            acc_l[qi] = MFMA(af0, ONES, acc_l[qi]);
            acc_l[qi] = MFMA(af1, ONES, acc_l[qi]);
        }
    }

    for (int qi = 0; qi < 2; qi++) {
        float ar[4];
        for (int r = 0; r < 4; r++) ar[r] = 1.0f / acc_l[qi][r];
        for (int dt = 0; dt < 4; dt++)
            for (int r = 0; r < 4; r++) {
                int row = qw + 16 * qi + 4 * q4 + r;
                xatt[(rowbase + row) * 768 + h * 64 + 16 * dt + lm] =
                    f2bf(acc[qi][dt][r] * ar[r]);
            }
    }
}

extern "C" void kernel_launch(void* const* d_in, const int* in_sizes, int n_in,
                              void* d_out, int out_size, void* d_ws, size_t ws_size,
                              hipStream_t stream)
{
    const float* x   = (const float*)d_in[0];
    const float* wq  = (const float*)d_in[1];
    const float* bq  = (const float*)d_in[2];
    const float* wkv = (const float*)d_in[3];
    const float* bkv = (const float*)d_in[4];
    const float* wp  = (const float*)d_in[5];
    const float* bp  = (const float*)d_in[6];
    float* out = (float*)d_out;

    char* ws = (char*)d_ws;
    u16* xb    = (u16*)(ws);                  // x bf16        [8192][768]   12.6 MB
    u16* wtqkv = (u16*)(ws + 12582912);       // W_qkv^T bf16  [2304][768]    3.5 MB
    u16* wtp   = (u16*)(ws + 16121856);       // W_p^T bf16    [768][768]     1.2 MB
    u16* qkvb  = (u16*)(ws + 17301504);       // q|k bf16      [8192][2304]  37.7 MB (V cols unused)
    u16* xatt  = (u16*)(ws + 55050240);       // attn out bf16 [8192][768]   12.6 MB
    u16* vtg   = (u16*)(ws + 67632128);       // V^T bf16 [48][64][2048]     12.6 MB

    prep_kernel<<<8448, 256, 0, stream>>>(x, wq, wkv, wp, xb, wtqkv, wtp);

    gemm128<<<1152, 256, 0, stream>>>(
        xb, wtqkv, bq, bkv, 768, qkvb, vtg, 8192, 2304, 768);

    attn_kernel<<<768, 256, 0, stream>>>(qkvb, vtg, xatt);

    gemm_n64<<<768, 256, 0, stream>>>(
        xatt, wtp, bp, out, 8192, 768, 768);
}

// Round 14
// 191.797 us; speedup vs baseline: 1.3662x; 1.0019x over previous
//
#include <hip/hip_runtime.h>

typedef unsigned short u16;
typedef __attribute__((ext_vector_type(8))) short bf16x8;
typedef __attribute__((ext_vector_type(4))) float f32x4;

#define MFMA(a, b, c) __builtin_amdgcn_mfma_f32_16x16x32_bf16(a, b, c, 0, 0, 0)
#define LOG2E 1.44269504088896340736f

__device__ __forceinline__ u16 f2bf(float f) {
    union { float f; unsigned u; } v; v.f = f;
    unsigned r = v.u + 0x7fffu + ((v.u >> 16) & 1u);   // RNE
    return (u16)(r >> 16);
}
__device__ __forceinline__ float bf2f(u16 h) {
    union { unsigned u; float f; } v; v.u = ((unsigned)h) << 16;
    return v.f;
}
// single-instruction packed f32->bf16 (RNE). Verified R2/R4-R10.
__device__ __forceinline__ unsigned pkbf(float a, float b) {
    unsigned r;
    asm("v_cvt_pk_bf16_f32 %0, %1, %2" : "=v"(r) : "v"(a), "v"(b));
    return r;
}
__device__ __forceinline__ u16 cvt1bf(float a) {
    return (u16)pkbf(a, a);
}
__device__ __forceinline__ float ex2(float x) {
#if __has_builtin(__builtin_amdgcn_exp2f)
    return __builtin_amdgcn_exp2f(x);
#else
    return exp2f(x);
#endif
}
__device__ __forceinline__ bf16x8 frag_from(unsigned a, unsigned b, unsigned c, unsigned d) {
    uint4 v; v.x = a; v.y = b; v.z = c; v.w = d;
    return __builtin_bit_cast(bf16x8, v);
}

// async global->LDS, 16B per lane. LDS dest = wave-uniform base + lane*16.
__device__ __forceinline__ void g2l16(const void* g, void* lds_base) {
    __builtin_amdgcn_global_load_lds(
        (const __attribute__((address_space(1))) unsigned*)(unsigned long long)(uintptr_t)g,
        (__attribute__((address_space(3))) unsigned*)(unsigned)(uintptr_t)lds_base,
        16, 0, 0);
}

// R13 lesson (banked): hipLaunchCooperativeKernel is incompatible with the
// harness's graph-capture replay (direct launch was CORRECT, absmax 1.46e-3,
// but the captured-graph re-run failed). Megakernel path abandoned; back to
// the R10-proven 4-kernel pipeline.

// ---- fused prep: x fp32->bf16 convert  +  3 weight transpose+converts ----
__global__ __launch_bounds__(256) void prep_kernel(
    const float* __restrict__ x, const float* __restrict__ wq,
    const float* __restrict__ wkv, const float* __restrict__ wp,
    u16* __restrict__ xb, u16* __restrict__ wtqkv, u16* __restrict__ wtp)
{
    int bz = blockIdx.x;
    int t = threadIdx.x;
    if (bz < 6144) {
        int i = (bz * 256 + t) * 4;
        float4 v = *(const float4*)&x[i];
        uint2 o;
        o.x = pkbf(v.x, v.y);
        o.y = pkbf(v.z, v.w);
        *(uint2*)&xb[i] = o;
        return;
    }
    __shared__ float tile[32][33];
    const float* W; u16* Wt; int cols; int r = bz - 6144;
    if (r < 576)       { W = wq;  Wt = wtqkv;             cols = 768;  }
    else if (r < 1728) { W = wkv; Wt = wtqkv + 768 * 768; cols = 1536; r -= 576; }
    else               { W = wp;  Wt = wtp;               cols = 768;  r -= 1728; }
    int nbx = cols / 32;
    int bx = (r % nbx) * 32, by = (r / nbx) * 32;
    int tx = t & 31, ty = t >> 5;
    for (int i = 0; i < 4; i++)
        tile[ty + 8 * i][tx] = W[(size_t)(by + ty + 8 * i) * cols + bx + tx];
    __syncthreads();
    for (int i = 0; i < 4; i++)
        Wt[(size_t)(bx + ty + 8 * i) * 768 + by + tx] = cvt1bf(tile[tx][ty + 8 * i]);
}

// ------- GEMM1: C[M][2304] = A[M][768]·Bt[2304][768]^T + bias, 128x128, BK=64.
// Exact R10 (proven ~42 µs): 34,816 B LDS, (256,4), cvt1bf epilogue.
__global__ __launch_bounds__(256, 4) void gemm128(
    const u16* __restrict__ A, const u16* __restrict__ Bt,
    const float* __restrict__ bias0, const float* __restrict__ bias1, int bsplit,
    u16* __restrict__ outB, u16* __restrict__ vtg, int M, int N, int K)
{
    __shared__ __align__(16) u16 smem[17408];   // 34,816 B
    u16* As = smem;
    u16* Bs = smem + 8192;
    u16* Cs = smem;

    int gid = blockIdx.x;
    int bmi = ((gid & 7) << 3) | ((gid >> 3) & 7);   // 0..63
    int bni = gid >> 6;                               // 0..17
    int bm = bmi * 128, bn = bni * 128;

    int t = threadIdx.x;
    int w = t >> 6, l = t & 63, q4 = l >> 4, lm = l & 15, lm7 = l & 7;
    int wm = (w >> 1) * 64, wn = (w & 1) * 64;

    f32x4 acc[4][4];
    for (int i = 0; i < 4; i++) for (int j = 0; j < 4; j++) acc[i][j] = (f32x4){0, 0, 0, 0};

    int srow = l >> 3;
    int schunk = (l & 7) ^ srow;

    for (int kt = 0; kt < K; kt += 64) {
        for (int p = 0; p < 4; p++) {
            int row = p * 32 + w * 8 + srow;
            g2l16(&A [(size_t)(bm + row) * K + kt + schunk * 8], &As[(p * 32 + w * 8) * 64]);
            g2l16(&Bt[(size_t)(bn + row) * K + kt + schunk * 8], &Bs[(p * 32 + w * 8) * 64]);
        }
        __syncthreads();
        for (int kc = 0; kc < 2; kc++) {
            bf16x8 a[4], b[4];
            for (int i = 0; i < 4; i++)
                a[i] = *(const bf16x8*)&As[(wm + 16 * i + lm) * 64 + ((4 * kc + q4) ^ lm7) * 8];
            for (int j = 0; j < 4; j++)
                b[j] = *(const bf16x8*)&Bs[(wn + 16 * j + lm) * 64 + ((4 * kc + q4) ^ lm7) * 8];
            for (int i = 0; i < 4; i++)
                for (int j = 0; j < 4; j++)
                    acc[i][j] = MFMA(a[i], b[j], acc[i][j]);
        }
        __syncthreads();
    }

    if (bn < 1536) {
        // Q/K: row-major repack (stride 132) then coalesced b128 stores
        for (int i = 0; i < 4; i++)
            for (int j = 0; j < 4; j++) {
                int col = bn + wn + 16 * j + lm;
                float bv = (col < bsplit) ? bias0[col] : bias1[col - bsplit];
                for (int r = 0; r < 4; r++)
                    Cs[(wm + 16 * i + 4 * q4 + r) * 132 + wn + 16 * j + lm] =
                        cvt1bf(acc[i][j][r] + bv);
            }
        __syncthreads();
        int row = t >> 1, c0 = (t & 1) * 8;
        for (int s = 0; s < 8; s++)
            *(uint4*)&outB[(size_t)(bm + row) * N + bn + c0 + s * 16] =
                *(const uint4*)&Cs[row * 132 + c0 + s * 16];
    } else {
        // V: TRANSPOSED repack Cs[col][row] (packed b64 writes along rows)
        for (int i = 0; i < 4; i++)
            for (int j = 0; j < 4; j++) {
                int cl = wn + 16 * j + lm;
                float bv = bias1[bn + cl - bsplit];
                uint2 pk;
                pk.x = pkbf(acc[i][j][0] + bv, acc[i][j][1] + bv);
                pk.y = pkbf(acc[i][j][2] + bv, acc[i][j][3] + bv);
                *(uint2*)&Cs[cl * 132 + wm + 16 * i + 4 * q4] = pk;
            }
        __syncthreads();
        int c = t >> 1, half = t & 1;
        int d = c & 63, hloc = c >> 6;
        int b = bm >> 11;
        int bh = b * 12 + ((bn - 1536) >> 6) + hloc;
        size_t rowoff = ((size_t)bh * 64 + d) * 2048 + (bm & 2047) + half * 64;
        const u16* base = &Cs[c * 132 + half * 64];
        for (int oct = 0; oct < 8; oct++) {
            int n0 = 32 * (oct >> 2) + 4 * (oct & 3);
            uint2 lo = *(const uint2*)&base[n0];
            uint2 hi = *(const uint2*)&base[n0 + 16];
            uint4 o; o.x = lo.x; o.y = lo.y; o.z = hi.x; o.w = hi.y;
            *(uint4*)&vtg[rowoff + oct * 8] = o;
        }
    }
}

// ------- GEMM2: out[M][768] fp32 = A[M][K]·Bt[768][K]^T + bias. 128x64 tile, BK=64.
// R14 change: LDS DOUBLE-BUFFERED prefetch (attn's proven pattern). The R10
// version staged the CURRENT tile then immediately barrier-drained — every
// K-step ate a full L2-latency drain with zero load/compute overlap. Now:
// loop-top barrier drains LAST iter's prefetch; issue NEXT tile post-barrier;
// compute current. One barrier per K-step instead of two.
// LDS 48 KB (2 x (As 16K | Bs 8K)), (256,3): 3 blocks/CU x 48 KB = 144 KB,
// VGPR cap ~170 >> ~100 used (R8 lesson checked). Epilogue Cf overlays base.
__global__ __launch_bounds__(256, 3) void gemm_n64(
    const u16* __restrict__ A, const u16* __restrict__ Bt,
    const float* __restrict__ bias, float* __restrict__ outF, int M, int N, int K)
{
    __shared__ __align__(16) u16 smem[24576];   // 48 KB
    float* Cf = (float*)smem;                   // [64][68] fp32 epilogue overlay (17.4 KB)

    int gid = blockIdx.x;
    int bmi = ((gid & 7) << 3) | ((gid >> 3) & 7);   // 0..63
    int bni = gid >> 6;                               // 0..11
    int bm = bmi * 128, bn = bni * 64;

    int t = threadIdx.x;
    int w = t >> 6, l = t & 63, q4 = l >> 4, lm = l & 15, lm7 = l & 7;
    int wm = (w >> 1) * 64, wn = (w & 1) * 32;

    f32x4 acc[4][2];
    for (int i = 0; i < 4; i++) for (int j = 0; j < 2; j++) acc[i][j] = (f32x4){0, 0, 0, 0};

    int srow = l >> 3;
    int schunk = (l & 7) ^ srow;

    // stage K-tile kt into buffer b (As at b*12288, Bs at b*12288+8192)
    auto stage = [&](int b, int kt) {
        u16* As = smem + b * 12288;
        u16* Bs = As + 8192;
        for (int p = 0; p < 4; p++) {
            int row = p * 32 + w * 8 + srow;
            g2l16(&A[(size_t)(bm + row) * K + kt + schunk * 8], &As[(p * 32 + w * 8) * 64]);
        }
        for (int p = 0; p < 2; p++) {
            int row = p * 32 + w * 8 + srow;
            g2l16(&Bt[(size_t)(bn + row) * K + kt + schunk * 8], &Bs[(p * 32 + w * 8) * 64]);
        }
    };

    stage(0, 0);
    int buf = 0;
    for (int kt = 0; kt < K; kt += 64) {
        __syncthreads();                         // drains prefetch for 'buf' (vmcnt0 before barrier)
        if (kt + 64 < K) stage(buf ^ 1, kt + 64);
        const u16* As = smem + buf * 12288;
        const u16* Bs = As + 8192;
        for (int kc = 0; kc < 2; kc++) {
            bf16x8 a[4], b[2];
            for (int i = 0; i < 4; i++)
                a[i] = *(const bf16x8*)&As[(wm + 16 * i + lm) * 64 + ((4 * kc + q4) ^ lm7) * 8];
            for (int j = 0; j < 2; j++)
                b[j] = *(const bf16x8*)&Bs[(wn + 16 * j + lm) * 64 + ((4 * kc + q4) ^ lm7) * 8];
            for (int i = 0; i < 4; i++)
                for (int j = 0; j < 2; j++)
                    acc[i][j] = MFMA(a[i], b[j], acc[i][j]);
        }
        buf ^= 1;
    }
    __syncthreads();                             // all reads done before Cf overlay

    // epilogue: two 64-row half-tiles via LDS, fully-coalesced float4 stores
    for (int round = 0; round < 2; round++) {
        if (round) __syncthreads();
        if ((w >> 1) == round) {
            for (int i = 0; i < 4; i++)
                for (int j = 0; j < 2; j++) {
                    int cl = wn + 16 * j + lm;
                    float bv = bias[bn + cl];
                    for (int r = 0; r < 4; r++)
                        Cf[(16 * i + 4 * q4 + r) * 68 + cl] = acc[i][j][r] + bv;
                }
        }
        __syncthreads();
        int row = t >> 4, c4 = (t & 15) * 4;
        for (int s = 0; s < 4; s++) {
            int rr = row + s * 16;
            *(float4*)&outF[(size_t)(bm + round * 64 + rr) * N + bn + c4] =
                *(const float4*)&Cf[rr * 68 + c4];
        }
    }
}

// ---------------- fused flash attention (exact R10, proven 54.6 µs) ----------------
// Issue-saturated: MfmaUtil 44 + VALUBusy 44 + DS 12 = 100%; stagger/setprio
// nulls confirm binding resource is per-SIMD issued work.
__global__ __launch_bounds__(256, 3) void attn_kernel(const u16* __restrict__ qkv,
                                                      const u16* __restrict__ vtg,
                                                      u16* __restrict__ xatt)
{
    __shared__ __align__(16) u16 smem[16384];   // 32,768 B

    int gid = blockIdx.x;
    int bh = gid % 48, qt = gid / 48;
    int b = bh / 12, h = bh % 12;

    int t = threadIdx.x;
    int w = t >> 6, l = t & 63, q4 = l >> 4, lm = l & 15, lm7 = l & 7;
    int qw = qt * 128 + w * 32;
    size_t rowbase = (size_t)b * 2048;

    int srow = l >> 3;
    int schunk = (l & 7) ^ srow;
    const u16* kp[2];
    const u16* vp[2];
    for (int p = 0; p < 2; p++) {
        int row = w * 16 + p * 8 + srow;
        kp[p] = &qkv[(rowbase + row) * 2304 + 768 + h * 64 + schunk * 8];
        vp[p] = &vtg[((size_t)bh * 64 + row) * 2048 + schunk * 8];
    }

    bf16x8 qf[2][2];
    for (int qi = 0; qi < 2; qi++) {
        size_t row = rowbase + qw + 16 * qi + lm;
        for (int kq = 0; kq < 2; kq++) {
            bf16x8 raw = *(const bf16x8*)&qkv[row * 2304 + h * 64 + kq * 32 + q4 * 8];
            bf16x8 sc;
            for (int j = 0; j < 8; j++) sc[j] = (short)f2bf(bf2f((u16)raw[j]) * (0.125f * LOG2E));
            qf[qi][kq] = sc;
        }
    }

    // all-ones bf16 B-fragment for the denominator MFMA
    const bf16x8 ONES = frag_from(0x3F803F80u, 0x3F803F80u, 0x3F803F80u, 0x3F803F80u);

    int offA = lm * 64 + (q4 ^ lm7) * 8;
    int offB = lm * 64 + ((4 | q4) ^ lm7) * 8;

    f32x4 acc[2][4];
    f32x4 acc_l[2];
    for (int qi = 0; qi < 2; qi++) {
        for (int dt = 0; dt < 4; dt++) acc[qi][dt] = (f32x4){0, 0, 0, 0};
        acc_l[qi] = (f32x4){0, 0, 0, 0};
    }

    for (int p = 0; p < 2; p++) {
        g2l16(kp[p], smem + (w * 16 + p * 8) * 64);
        g2l16(vp[p], smem + 8192 + (w * 16 + p * 8) * 64);
    }

    const size_t KSTEP = (size_t)64 * 2304;
    for (int it = 0; it < 32; it++) {
        __syncthreads();
        int buf = it & 1;
        if (it + 1 < 32) {
            int nbuf = buf ^ 1;
            for (int p = 0; p < 2; p++) {
                kp[p] += KSTEP;
                vp[p] += 64;
                g2l16(kp[p], smem + nbuf * 4096 + (w * 16 + p * 8) * 64);
                g2l16(vp[p], smem + 8192 + nbuf * 4096 + (w * 16 + p * 8) * 64);
            }
        }
        const u16* Kb = smem + buf * 4096;
        const u16* Vb = smem + 8192 + buf * 4096;

        f32x4 s[2][4];
        for (int kt2 = 0; kt2 < 4; kt2++) {
            bf16x8 kf0 = *(const bf16x8*)&Kb[kt2 * 1024 + offA];
            bf16x8 kf1 = *(const bf16x8*)&Kb[kt2 * 1024 + offB];
            for (int qi = 0; qi < 2; qi++) {
                f32x4 z = {0, 0, 0, 0};
                z = MFMA(kf0, qf[qi][0], z);
                z = MFMA(kf1, qf[qi][1], z);
                s[qi][kt2] = z;
            }
        }

        bf16x8 vf0[4], vf1[4];
        for (int dt = 0; dt < 4; dt++) {
            vf0[dt] = *(const bf16x8*)&Vb[dt * 1024 + offA];
            vf1[dt] = *(const bf16x8*)&Vb[dt * 1024 + offB];
        }

        for (int qi = 0; qi < 2; qi++) {
            uint2 pk[4];
            for (int kt2 = 0; kt2 < 4; kt2++) {
                float p0 = ex2(s[qi][kt2][0]);
                float p1 = ex2(s[qi][kt2][1]);
                float p2 = ex2(s[qi][kt2][2]);
                float p3 = ex2(s[qi][kt2][3]);
                pk[kt2].x = pkbf(p0, p1);
                pk[kt2].y = pkbf(p2, p3);
            }

            bf16x8 af0 = frag_from(pk[0].x, pk[0].y, pk[1].x, pk[1].y);
            bf16x8 af1 = frag_from(pk[2].x, pk[2].y, pk[3].x, pk[3].y);
            for (int dt = 0; dt < 4; dt++) {
                acc[qi][dt] = MFMA(af0, vf0[dt], acc[qi][dt]);
                acc[qi][dt] = MFMA(af1, vf1[dt], acc[qi][dt]);
            }
            // denominator on the MFMA pipe (ones-column trick)
            acc_l[qi] = MFMA(af0, ONES, acc_l[qi]);
            acc_l[qi] = MFMA(af1, ONES, acc_l[qi]);
        }
    }

    for (int qi = 0; qi < 2; qi++) {
        float ar[4];
        for (int r = 0; r < 4; r++) ar[r] = 1.0f / acc_l[qi][r];
        for (int dt = 0; dt < 4; dt++)
            for (int r = 0; r < 4; r++) {
                int row = qw + 16 * qi + 4 * q4 + r;
                xatt[(rowbase + row) * 768 + h * 64 + 16 * dt + lm] =
                    f2bf(acc[qi][dt][r] * ar[r]);
            }
    }
}

extern "C" void kernel_launch(void* const* d_in, const int* in_sizes, int n_in,
                              void* d_out, int out_size, void* d_ws, size_t ws_size,
                              hipStream_t stream)
{
    const float* x   = (const float*)d_in[0];
    const float* wq  = (const float*)d_in[1];
    const float* bq  = (const float*)d_in[2];
    const float* wkv = (const float*)d_in[3];
    const float* bkv = (const float*)d_in[4];
    const float* wp  = (const float*)d_in[5];
    const float* bp  = (const float*)d_in[6];
    float* out = (float*)d_out;

    char* ws = (char*)d_ws;
    u16* xb    = (u16*)(ws);                  // x bf16        [8192][768]   12.6 MB
    u16* wtqkv = (u16*)(ws + 12582912);       // W_qkv^T bf16  [2304][768]    3.5 MB
    u16* wtp   = (u16*)(ws + 16121856);       // W_p^T bf16    [768][768]     1.2 MB
    u16* qkvb  = (u16*)(ws + 17301504);       // q|k bf16      [8192][2304]  37.7 MB (V cols unused)
    u16* xatt  = (u16*)(ws + 55050240);       // attn out bf16 [8192][768]   12.6 MB
    u16* vtg   = (u16*)(ws + 67632128);       // V^T bf16 [48][64][2048]     12.6 MB

    prep_kernel<<<8448, 256, 0, stream>>>(x, wq, wkv, wp, xb, wtqkv, wtp);

    gemm128<<<1152, 256, 0, stream>>>(
        xb, wtqkv, bq, bkv, 768, qkvb, vtg, 8192, 2304, 768);

    attn_kernel<<<768, 256, 0, stream>>>(qkvb, vtg, xatt);

    gemm_n64<<<768, 256, 0, stream>>>(
        xatt, wtp, bp, out, 8192, 768, 768);
}